// Round 7
// baseline (98.699 us; speedup 1.0000x reference)
//
#include <hip/hip_runtime.h>
#include <math.h>

#define KDIM 100
#define DDIM 64

typedef __bf16 bf16x8 __attribute__((ext_vector_type(8)));
typedef float  f32x4  __attribute__((ext_vector_type(4)));

struct Weights {
  const float *w1, *b1, *w2, *b2, *w3, *b3, *w4, *b4, *w5, *b5;
};

// ---------------- mlp LDS layout (floats) ----------------
constexpr int L_VEC = 0;      // [4][100] USUM, ISUM, US, IS
constexpr int L_PA  = 400;    // [4][128] PA1,PB1,PA2,PB2
constexpr int L_B1  = 912;    // [2][128]   (L_B1..L_W5 = 512 floats, = tail layout)
constexpr int L_B2  = 1168;   // [2][64]
constexpr int L_B3  = 1296;   // [2][32]
constexpr int L_B4  = 1360;   // [2][16]
constexpr int L_W5  = 1392;   // [2][16]
constexpr int L_C   = 1424;   // [2][128] per-net per-row outputs
constexpr int SM_F  = 1680;
constexpr int H2T_BYTE   = SM_F * 4;                    // 6720 (16B aligned)
constexpr int H2T_WBYTES = 16 * 72 * 2;                 // 2304 per wave (chunked)
constexpr int H3T_BYTE   = H2T_BYTE + 8 * H2T_WBYTES;   // 25152
constexpr int H3T_WBYTES = 16 * 40 * 2;                 // 1280 per wave
constexpr int SM_BYTES   = H3T_BYTE + 8 * H3T_WBYTES;   // 35392 B -> 4 blocks/CU

// ---------------- kernel 1: rowsums + wfrag pack + bias tail ----------------
// wfrag: [net(2)][frag f(21)][lane(64)][8 bf16]; f 0-15 = W2(k*4+n), 16-19 = W3, 20 = W4.
__global__ void prep_kernel(const float* __restrict__ user_emb,
                            const float* __restrict__ item_emb,
                            float* __restrict__ u_rowsum,
                            float* __restrict__ i_rowsum,
                            int NU, int NI, Weights N1, Weights N2,
                            __bf16* __restrict__ wfrag, float* __restrict__ tail) {
  const int tid  = threadIdx.x;
  const int lane = tid & 63;
  const int g = lane >> 4, c16 = lane & 15;
  const int gw = (blockIdx.x * blockDim.x + tid) >> 6;

  if (gw < 42) {
    const int net = gw / 21, f = gw % 21;
    const Weights W = net ? N2 : N1;
    bf16x8 v;
    if (f < 16) {
      const int k = f >> 2, n = f & 3;
      #pragma unroll
      for (int i = 0; i < 8; ++i) {
        const int kk = 32 * k + 8 * g + i, nn = 16 * n + c16;
        v[i] = (__bf16)((kk < 100 && nn < 50) ? W.w2[kk * 50 + nn] : 0.f);
      }
    } else if (f < 20) {
      const int t = f - 16, k = t >> 1, n = t & 1;
      #pragma unroll
      for (int i = 0; i < 8; ++i) {
        const int kk = 32 * k + 8 * g + i, nn = 16 * n + c16;
        v[i] = (__bf16)((kk < 50 && nn < 25) ? W.w3[kk * 25 + nn] : 0.f);
      }
    } else {
      #pragma unroll
      for (int i = 0; i < 8; ++i) {
        const int kk = 8 * g + i, nn = c16;
        v[i] = (__bf16)((kk < 25 && nn < 12) ? W.w4[kk * 12 + nn] : 0.f);
      }
    }
    *(bf16x8*)(wfrag + (size_t)gw * 512 + lane * 8) = v;
  }

  if (blockIdx.x == 0) {
    for (int e = tid; e < 512; e += 256) {
      float v;
      if (e < 256)      { const int j = e & 127; const Weights W = (e & 128) ? N2 : N1; v = (j < 100) ? W.b1[j] : 0.f; }
      else if (e < 384) { const int t = e - 256; const int j = t & 63; const Weights W = (t & 64) ? N2 : N1; v = (j < 50) ? W.b2[j] : 0.f; }
      else if (e < 448) { const int t = e - 384; const int j = t & 31; const Weights W = (t & 32) ? N2 : N1; v = (j < 25) ? W.b3[j] : 0.f; }
      else if (e < 480) { const int t = e - 448; const int j = t & 15; const Weights W = (t & 16) ? N2 : N1; v = (j < 12) ? W.b4[j] : 0.f; }
      else              { const int t = e - 480; const int j = t & 15; const Weights W = (t & 16) ? N2 : N1; v = (j < 12) ? W.w5[j] : 0.f; }
      tail[e] = v;
    }
  }

  // coalesced rowsums: wave = 4 rows
  const int NR = NU + NI;
  const int chunk = lane & 15, lrow = lane >> 4;
  const int nwave = (gridDim.x * blockDim.x) >> 6;
  for (int base = gw * 4; base < NR; base += nwave * 4) {
    const int r = base + lrow;
    float s = 0.f;
    if (r < NR) {
      const float* src = (r < NU) ? (user_emb + (size_t)r * DDIM)
                                  : (item_emb + (size_t)(r - NU) * DDIM);
      const float4 v4 = ((const float4*)src)[chunk];
      s = v4.x + v4.y + v4.z + v4.w;
    }
    s += __shfl_xor(s, 1); s += __shfl_xor(s, 2);
    s += __shfl_xor(s, 4); s += __shfl_xor(s, 8);
    if (chunk == 0 && r < NR) {
      if (r < NU) u_rowsum[r] = s; else i_rowsum[r - NU] = s;
    }
  }
}

// ---------------- kernel 2: batched layer-1 projections ----------------
// block = (batch-tile of 64) x (sel 0..3). PA[sel][b][j] = sum_k V[sel][b][k] w1[rb+k][j]
// sel: 0 = USUM@w1n1[0:100], 1 = ISUM@w1n1[100:200], 2 = US@w1n2[0:100], 3 = IS@w1n2[100:200]
__global__ void __launch_bounds__(256) proj_kernel(
    const int* __restrict__ user_idxs, const int* __restrict__ item_idxs,
    const int* __restrict__ uidx_t, const int* __restrict__ iidx_t,
    const float* __restrict__ uscr, const float* __restrict__ iscr,
    const float* __restrict__ u_rowsum, const float* __restrict__ i_rowsum,
    const float* __restrict__ n1w1, const float* __restrict__ n2w1,
    float* __restrict__ VG, float* __restrict__ PAG, int B)
{
  __shared__ float VT[100][68];     // [k][b_local], stride 68 (16B-aligned rows, spread banks)
  __shared__ float W1S[50][128];    // staged w1 k-half, cols 100..127 zero
  __shared__ int sidx[64];
  const int tid = threadIdx.x;
  const int sel = blockIdx.x & 3;
  const int bt  = blockIdx.x >> 2;
  const int b0  = bt * 64;

  if (tid < 64) {
    const int b = b0 + tid;
    const int bb = (b < B) ? b : (B - 1);
    sidx[tid] = (sel == 0 || sel == 2) ? user_idxs[bb] : item_idxs[bb];
  }
  __syncthreads();

  // gather V-tile: thread (bi, kq): k = kq + 4*i
  {
    const int bi = tid & 63, kq = tid >> 6;
    const size_t row = (size_t)sidx[bi] * KDIM;
    if (sel == 0) {
      #pragma unroll 5
      for (int i = 0; i < 25; ++i) { const int k = kq + 4 * i; VT[k][bi] = u_rowsum[uidx_t[row + k]]; }
    } else if (sel == 1) {
      #pragma unroll 5
      for (int i = 0; i < 25; ++i) { const int k = kq + 4 * i; VT[k][bi] = i_rowsum[iidx_t[row + k]]; }
    } else if (sel == 2) {
      #pragma unroll 5
      for (int i = 0; i < 25; ++i) { const int k = kq + 4 * i; VT[k][bi] = uscr[row + k]; }
    } else {
      #pragma unroll 5
      for (int i = 0; i < 25; ++i) { const int k = kq + 4 * i; VT[k][bi] = iscr[row + k]; }
    }
  }

  const float* w1 = (sel < 2) ? n1w1 : n2w1;
  const int rb = (sel & 1) * KDIM;
  const int jg = tid & 15, bg = tid >> 4;   // j0 = 8*jg (covers 128), b-base = 4*bg
  float acc[4][8];
  #pragma unroll
  for (int bi = 0; bi < 4; ++bi)
    #pragma unroll
    for (int ji = 0; ji < 8; ++ji) acc[bi][ji] = 0.f;

  for (int kh = 0; kh < 2; ++kh) {
    __syncthreads();
    for (int e = tid; e < 50 * 128; e += 256) {
      const int k = e >> 7, j = e & 127;
      W1S[k][j] = (j < KDIM) ? w1[(size_t)(rb + kh * 50 + k) * KDIM + j] : 0.f;
    }
    __syncthreads();
    #pragma unroll 2
    for (int k = 0; k < 50; ++k) {
      const float4 v  = *(const float4*)&VT[kh * 50 + k][4 * bg];
      const float4 w0 = *(const float4*)&W1S[k][8 * jg];
      const float4 w1v = *(const float4*)&W1S[k][8 * jg + 4];
      const float vv[4] = {v.x, v.y, v.z, v.w};
      const float ww[8] = {w0.x, w0.y, w0.z, w0.w, w1v.x, w1v.y, w1v.z, w1v.w};
      #pragma unroll
      for (int bi = 0; bi < 4; ++bi)
        #pragma unroll
        for (int ji = 0; ji < 8; ++ji)
          acc[bi][ji] = fmaf(vv[bi], ww[ji], acc[bi][ji]);
    }
  }

  // store PA[sel][b][0..127]
  #pragma unroll
  for (int bi = 0; bi < 4; ++bi) {
    const int b = b0 + 4 * bg + bi;
    if (b < B) {
      float* dst = PAG + ((size_t)sel * B + b) * 128 + 8 * jg;
      #pragma unroll
      for (int ji = 0; ji < 8; ++ji) dst[ji] = acc[bi][ji];
    }
  }
  // store V[sel][b][0..99] (for mlp row scalars)
  {
    const int b = b0 + (tid >> 2), qq = tid & 3;
    if (b < B) {
      float* dst = VG + ((size_t)sel * B + b) * KDIM + qq * 25;
      #pragma unroll 5
      for (int i = 0; i < 25; ++i) dst[i] = VT[qq * 25 + i][tid >> 2];
    }
  }
}

// ---------------- kernel 3: barrier-free per-wave MFMA chain ----------------
// 512 threads = 8 waves; wave wv: net = wv>>2, quarter q = wv&3 (rows 25q..25q+24).
__global__ void __launch_bounds__(512, 4) mlp_kernel(
    const float* __restrict__ VG, const float* __restrict__ PAG,
    const float* __restrict__ tail,
    const float* __restrict__ n1b5, const float* __restrict__ n2b5,
    const __bf16* __restrict__ wfrag, float* __restrict__ out, int B)
{
  __shared__ __align__(16) char smem[SM_BYTES];
  float* sm = (float*)smem;
  const int tid  = threadIdx.x;
  const int lane = tid & 63;
  const int wv   = tid >> 6;
  const int g    = lane >> 4;
  const int c16  = lane & 15;
  const int b    = blockIdx.x;

  // ---- phase 0: coalesced loads of V, PA, biases
  if (tid < 400) sm[L_VEC + tid] = VG[((size_t)(tid / 100) * B + b) * KDIM + (tid % 100)];
  sm[L_PA + tid] = PAG[((size_t)(tid >> 7) * B + b) * 128 + (tid & 127)];
  sm[L_B1 + tid] = tail[tid];    // 512 floats == L_B1..L_W5 exactly
  __syncthreads();

  // ---- per-wave independent MFMA chain
  const int net = wv >> 2;
  const int q   = wv & 3;
  const int r0  = 25 * q;
  const int vA  = net ? (L_VEC + 0)   : (L_VEC + 200);  // net1: sums, net0: scores
  const int vB  = net ? (L_VEC + 100) : (L_VEC + 300);
  const int pAo = L_PA + net * 256;
  const int pBo = pAo + 128;
  __bf16* h2t = (__bf16*)(smem + H2T_BYTE + wv * H2T_WBYTES);  // [16][72]
  __bf16* h3t = (__bf16*)(smem + H3T_BYTE + wv * H3T_WBYTES);  // [16][40]
  const bf16x8* WF = (const bf16x8*)wfrag;
  const int fb = net * 21;
  const float b5v = net ? n2b5[0] : n1b5[0];

  float sAr[2], sBr[2];
  #pragma unroll
  for (int m = 0; m < 2; ++m) {
    const int row = r0 + 16 * m + c16;
    const int rr = row < KDIM ? row : (KDIM - 1);   // clamp; pad rows filtered at write
    sAr[m] = sm[vA + rr]; sBr[m] = sm[vB + rr];
  }

  // ---- layer 2: acc2[m][n], h1 generated in-register
  f32x4 acc2[2][4];
  #pragma unroll
  for (int m = 0; m < 2; ++m)
    #pragma unroll
    for (int n = 0; n < 4; ++n) acc2[m][n] = (f32x4){0.f, 0.f, 0.f, 0.f};

  #pragma unroll
  for (int k = 0; k < 4; ++k) {
    bf16x8 bw[4];
    #pragma unroll
    for (int n = 0; n < 4; ++n) bw[n] = WF[(size_t)(fb + k * 4 + n) * 64 + lane];
    const int jb = 32 * k + 8 * g;
    float paf[8], pbf[8], b1f[8];
    #pragma unroll
    for (int i = 0; i < 8; ++i) {
      paf[i] = sm[pAo + jb + i];
      pbf[i] = sm[pBo + jb + i];
      b1f[i] = sm[L_B1 + net * 128 + jb + i];
    }
    #pragma unroll
    for (int m = 0; m < 2; ++m) {
      bf16x8 a;
      #pragma unroll
      for (int i = 0; i < 8; ++i)
        a[i] = (__bf16)fmaxf(fmaf(sAr[m], paf[i], fmaf(sBr[m], pbf[i], b1f[i])), 0.f);
      #pragma unroll
      for (int n = 0; n < 4; ++n)
        acc2[m][n] = __builtin_amdgcn_mfma_f32_16x16x32_bf16(a, bw[n], acc2[m][n], 0, 0, 0);
    }
  }

  // ---- layer 3/4/5 weights + scalars
  bf16x8 W3f[2][2];
  #pragma unroll
  for (int k = 0; k < 2; ++k)
    #pragma unroll
    for (int n = 0; n < 2; ++n)
      W3f[k][n] = WF[(size_t)(fb + 16 + k * 2 + n) * 64 + lane];
  const bf16x8 W4f = WF[(size_t)(fb + 20) * 64 + lane];
  const float b4v = sm[L_B4 + net * 16 + c16];
  const float w5v = sm[L_W5 + net * 16 + c16];

  // ---- m-chunked tail: per 16-row chunk, reuse small h2t/h3t buffers
  #pragma unroll
  for (int mm = 0; mm < 2; ++mm) {
    // h2 epilogue (chunk mm): local rows 4g+r
    #pragma unroll
    for (int n = 0; n < 4; ++n) {
      const float b2v = sm[L_B2 + net * 64 + 16 * n + c16];
      #pragma unroll
      for (int r = 0; r < 4; ++r)
        h2t[(4 * g + r) * 72 + 16 * n + c16] = (__bf16)fmaxf(acc2[mm][n][r] + b2v, 0.f);
    }
    asm volatile("s_waitcnt lgkmcnt(0)" ::: "memory");
    __builtin_amdgcn_sched_barrier(0);

    // layer 3 (chunk mm)
    f32x4 acc3[2];
    #pragma unroll
    for (int n = 0; n < 2; ++n) acc3[n] = (f32x4){0.f, 0.f, 0.f, 0.f};
    #pragma unroll
    for (int k = 0; k < 2; ++k) {
      const bf16x8 a = *(const bf16x8*)(h2t + c16 * 72 + 32 * k + 8 * g);
      #pragma unroll
      for (int n = 0; n < 2; ++n)
        acc3[n] = __builtin_amdgcn_mfma_f32_16x16x32_bf16(a, W3f[k][n], acc3[n], 0, 0, 0);
    }
    #pragma unroll
    for (int n = 0; n < 2; ++n) {
      const float b3v = sm[L_B3 + net * 32 + 16 * n + c16];
      #pragma unroll
      for (int r = 0; r < 4; ++r)
        h3t[(4 * g + r) * 40 + 16 * n + c16] = (__bf16)fmaxf(acc3[n][r] + b3v, 0.f);
    }
    asm volatile("s_waitcnt lgkmcnt(0)" ::: "memory");
    __builtin_amdgcn_sched_barrier(0);

    // layer 4 + 5 + per-row reduce (chunk mm)
    {
      const bf16x8 a = *(const bf16x8*)(h3t + c16 * 40 + 8 * g);
      const f32x4 z = {0.f, 0.f, 0.f, 0.f};
      const f32x4 acc4 = __builtin_amdgcn_mfma_f32_16x16x32_bf16(a, W4f, z, 0, 0, 0);
      #pragma unroll
      for (int r = 0; r < 4; ++r) {
        float v = fmaxf(acc4[r] + b4v, 0.f) * w5v;   // col pads contribute 0
        v += __shfl_xor(v, 1); v += __shfl_xor(v, 2);
        v += __shfl_xor(v, 4); v += __shfl_xor(v, 8);
        const int lrow = 16 * mm + 4 * g + r;
        if (c16 == 0 && lrow < 25)
          sm[L_C + net * 128 + r0 + lrow] = v + b5v;
      }
    }
  }
  __syncthreads();

  // ---- final: sum rows 0..99 of both nets -> sigmoid(mean)
  float v = 0.f;
  if (tid < KDIM) v = sm[L_C + tid] + sm[L_C + 128 + tid];
  if (tid < 128) {
    #pragma unroll
    for (int d = 1; d < 64; d <<= 1) v += __shfl_xor(v, d);
    if ((tid & 63) == 0) sm[tid >> 6] = v;
  }
  __syncthreads();
  if (tid == 0) out[b] = 1.f / (1.f + expf(-0.01f * (sm[0] + sm[1])));
}

extern "C" void kernel_launch(void* const* d_in, const int* in_sizes, int n_in,
                              void* d_out, int out_size, void* d_ws, size_t ws_size,
                              hipStream_t stream) {
  const int*   user_idxs = (const int*)d_in[0];
  const int*   item_idxs = (const int*)d_in[1];
  const int*   uidx_t    = (const int*)d_in[2];
  const int*   iidx_t    = (const int*)d_in[3];
  const float* uscr      = (const float*)d_in[4];
  const float* iscr      = (const float*)d_in[5];
  const float* uemb      = (const float*)d_in[6];
  const float* iemb      = (const float*)d_in[7];

  const int B  = in_sizes[0];
  const int NU = in_sizes[6] / DDIM;
  const int NI = in_sizes[7] / DDIM;

  Weights N1 { (const float*)d_in[8],  (const float*)d_in[9],
               (const float*)d_in[10], (const float*)d_in[11],
               (const float*)d_in[12], (const float*)d_in[13],
               (const float*)d_in[14], (const float*)d_in[15],
               (const float*)d_in[16], (const float*)d_in[17] };
  Weights N2 { (const float*)d_in[18], (const float*)d_in[19],
               (const float*)d_in[20], (const float*)d_in[21],
               (const float*)d_in[22], (const float*)d_in[23],
               (const float*)d_in[24], (const float*)d_in[25],
               (const float*)d_in[26], (const float*)d_in[27] };

  // workspace layout
  char* ws = (char*)d_ws;
  float* u_rowsum = (float*)ws;
  float* i_rowsum = u_rowsum + NU;
  size_t off = (((size_t)(NU + NI) * 4 + 1023) & ~(size_t)1023);
  __bf16* wfrag = (__bf16*)(ws + off);                 // 42*512 bf16
  float*  tail  = (float*)(wfrag + (size_t)42 * 512);  // 512 f32
  off += (((size_t)42 * 512 * 2 + 512 * 4 + 1023) & ~(size_t)1023);
  float* VG  = (float*)(ws + off);                     // [4][B][100]
  off += (size_t)4 * B * KDIM * 4;
  float* PAG = (float*)(ws + off);                     // [4][B][128]

  float* out = (float*)d_out;

  prep_kernel<<<1024, 256, 0, stream>>>(uemb, iemb, u_rowsum, i_rowsum, NU, NI, N1, N2, wfrag, tail);
  const int nbt = (B + 63) / 64;
  proj_kernel<<<nbt * 4, 256, 0, stream>>>(user_idxs, item_idxs, uidx_t, iidx_t,
                                           uscr, iscr, u_rowsum, i_rowsum,
                                           N1.w1, N2.w1, VG, PAG, B);
  mlp_kernel<<<B, 512, 0, stream>>>(VG, PAG, tail, N1.b5, N2.b5, wfrag, out, B);
}

// Round 8
// 86.670 us; speedup vs baseline: 1.1388x; 1.1388x over previous
//
#include <hip/hip_runtime.h>
#include <math.h>

#define KDIM 100
#define DDIM 64

typedef __bf16 bf16x8 __attribute__((ext_vector_type(8)));
typedef float  f32x4  __attribute__((ext_vector_type(4)));

struct Weights {
  const float *w1, *b1, *w2, *b2, *w3, *b3, *w4, *b4, *w5, *b5;
};

// ---------------- mlp LDS layout (floats) ----------------
constexpr int L_VEC = 0;      // [4][100] USUM, ISUM, US, IS
constexpr int L_PA  = 400;    // [4][128] PA1,PB1,PA2,PB2
constexpr int L_B1  = 912;    // [2][128]   (L_B1..L_W5 = 512 floats, = tail layout)
constexpr int L_B2  = 1168;   // [2][64]
constexpr int L_B3  = 1296;   // [2][32]
constexpr int L_B4  = 1360;   // [2][16]
constexpr int L_W5  = 1392;   // [2][16]
constexpr int L_C   = 1424;   // [2][128] per-net per-row outputs
constexpr int SM_F  = 1680;
constexpr int H2T_BYTE   = SM_F * 4;                    // 6720 (16B aligned)
constexpr int H2T_WBYTES = 16 * 72 * 2;                 // 2304 per wave (chunked)
constexpr int H3T_BYTE   = H2T_BYTE + 8 * H2T_WBYTES;   // 25152
constexpr int H3T_WBYTES = 16 * 40 * 2;                 // 1280 per wave
constexpr int SM_BYTES   = H3T_BYTE + 8 * H3T_WBYTES;   // 35392 B -> 4 blocks/CU

// ---------------- kernel 1: rowsums + wfrag pack + bias tail ----------------
// wfrag: [net(2)][frag f(21)][lane(64)][8 bf16]; f 0-15 = W2(k*4+n), 16-19 = W3, 20 = W4.
__global__ void prep_kernel(const float* __restrict__ user_emb,
                            const float* __restrict__ item_emb,
                            float* __restrict__ u_rowsum,
                            float* __restrict__ i_rowsum,
                            int NU, int NI, Weights N1, Weights N2,
                            __bf16* __restrict__ wfrag, float* __restrict__ tail) {
  const int tid  = threadIdx.x;
  const int lane = tid & 63;
  const int g = lane >> 4, c16 = lane & 15;
  const int gw = (blockIdx.x * blockDim.x + tid) >> 6;

  if (gw < 42) {
    const int net = gw / 21, f = gw % 21;
    const Weights W = net ? N2 : N1;
    bf16x8 v;
    if (f < 16) {
      const int k = f >> 2, n = f & 3;
      #pragma unroll
      for (int i = 0; i < 8; ++i) {
        const int kk = 32 * k + 8 * g + i, nn = 16 * n + c16;
        v[i] = (__bf16)((kk < 100 && nn < 50) ? W.w2[kk * 50 + nn] : 0.f);
      }
    } else if (f < 20) {
      const int t = f - 16, k = t >> 1, n = t & 1;
      #pragma unroll
      for (int i = 0; i < 8; ++i) {
        const int kk = 32 * k + 8 * g + i, nn = 16 * n + c16;
        v[i] = (__bf16)((kk < 50 && nn < 25) ? W.w3[kk * 25 + nn] : 0.f);
      }
    } else {
      #pragma unroll
      for (int i = 0; i < 8; ++i) {
        const int kk = 8 * g + i, nn = c16;
        v[i] = (__bf16)((kk < 25 && nn < 12) ? W.w4[kk * 12 + nn] : 0.f);
      }
    }
    *(bf16x8*)(wfrag + (size_t)gw * 512 + lane * 8) = v;
  }

  if (blockIdx.x == 0) {
    for (int e = tid; e < 512; e += 256) {
      float v;
      if (e < 256)      { const int j = e & 127; const Weights W = (e & 128) ? N2 : N1; v = (j < 100) ? W.b1[j] : 0.f; }
      else if (e < 384) { const int t = e - 256; const int j = t & 63; const Weights W = (t & 64) ? N2 : N1; v = (j < 50) ? W.b2[j] : 0.f; }
      else if (e < 448) { const int t = e - 384; const int j = t & 31; const Weights W = (t & 32) ? N2 : N1; v = (j < 25) ? W.b3[j] : 0.f; }
      else if (e < 480) { const int t = e - 448; const int j = t & 15; const Weights W = (t & 16) ? N2 : N1; v = (j < 12) ? W.b4[j] : 0.f; }
      else              { const int t = e - 480; const int j = t & 15; const Weights W = (t & 16) ? N2 : N1; v = (j < 12) ? W.w5[j] : 0.f; }
      tail[e] = v;
    }
  }

  // coalesced rowsums: wave = 4 rows
  const int NR = NU + NI;
  const int chunk = lane & 15, lrow = lane >> 4;
  const int nwave = (gridDim.x * blockDim.x) >> 6;
  for (int base = gw * 4; base < NR; base += nwave * 4) {
    const int r = base + lrow;
    float s = 0.f;
    if (r < NR) {
      const float* src = (r < NU) ? (user_emb + (size_t)r * DDIM)
                                  : (item_emb + (size_t)(r - NU) * DDIM);
      const float4 v4 = ((const float4*)src)[chunk];
      s = v4.x + v4.y + v4.z + v4.w;
    }
    s += __shfl_xor(s, 1); s += __shfl_xor(s, 2);
    s += __shfl_xor(s, 4); s += __shfl_xor(s, 8);
    if (chunk == 0 && r < NR) {
      if (r < NU) u_rowsum[r] = s; else i_rowsum[r - NU] = s;
    }
  }
}

// ---------------- kernel 2: batched layer-1 projections ----------------
// block = (batch-tile of 32) x (sel 0..3). PA[sel][b][j] = sum_k V[sel][b][k] w1[rb+k][j]
// sel: 0 = USUM@w1n1[0:100], 1 = ISUM@w1n1[100:200], 2 = US@w1n2[0:100], 3 = IS@w1n2[100:200]
__global__ void __launch_bounds__(256) proj_kernel(
    const int* __restrict__ user_idxs, const int* __restrict__ item_idxs,
    const int* __restrict__ uidx_t, const int* __restrict__ iidx_t,
    const float* __restrict__ uscr, const float* __restrict__ iscr,
    const float* __restrict__ u_rowsum, const float* __restrict__ i_rowsum,
    const float* __restrict__ n1w1, const float* __restrict__ n2w1,
    float* __restrict__ VG, float* __restrict__ PAG, int B)
{
  __shared__ float VT[100][36];     // [k][b_local]; stride 36 -> (144k+16b) 16B-aligned f4
  __shared__ float W1S[50][128];    // staged w1 k-half, cols 100..127 zero
  __shared__ int sidx[32];
  const int tid = threadIdx.x;
  const int sel = blockIdx.x & 3;
  const int b0  = (blockIdx.x >> 2) * 32;

  if (tid < 32) {
    const int b = b0 + tid;
    const int bb = (b < B) ? b : (B - 1);
    sidx[tid] = (sel & 1) ? item_idxs[bb] : user_idxs[bb];
  }
  __syncthreads();

  // gather V-tile: 8 threads per batch, k-strided (coalesced idx reads)
  {
    const int bl = tid >> 3, strip = tid & 7;
    const size_t row = (size_t)sidx[bl] * KDIM;
    if (sel == 0) {
      for (int k = strip; k < KDIM; k += 8) VT[k][bl] = u_rowsum[uidx_t[row + k]];
    } else if (sel == 1) {
      for (int k = strip; k < KDIM; k += 8) VT[k][bl] = i_rowsum[iidx_t[row + k]];
    } else if (sel == 2) {
      for (int k = strip; k < KDIM; k += 8) VT[k][bl] = uscr[row + k];
    } else {
      for (int k = strip; k < KDIM; k += 8) VT[k][bl] = iscr[row + k];
    }
  }

  const float* w1 = (sel < 2) ? n1w1 : n2w1;
  const int rb = (sel & 1) * KDIM;
  const int jg = tid & 31, bg = tid >> 5;   // j0 = 4*jg (128 j), batches 4*bg..4*bg+3
  float acc[4][4];
  #pragma unroll
  for (int bi = 0; bi < 4; ++bi)
    #pragma unroll
    for (int ji = 0; ji < 4; ++ji) acc[bi][ji] = 0.f;

  for (int kh = 0; kh < 2; ++kh) {
    __syncthreads();
    // stage w1 half: rows are exactly 25 float4; cols 100..127 zero
    for (int e = tid; e < 1600; e += 256) {
      const int k = e >> 5, s = e & 31;
      float4 v;
      if (s < 25) v = ((const float4*)(w1 + (size_t)(rb + kh * 50 + k) * KDIM))[s];
      else        v = make_float4(0.f, 0.f, 0.f, 0.f);
      *(float4*)&W1S[k][4 * s] = v;
    }
    __syncthreads();
    #pragma unroll 2
    for (int k = 0; k < 50; ++k) {
      const float4 v = *(const float4*)&VT[kh * 50 + k][4 * bg];
      const float4 w = *(const float4*)&W1S[k][4 * jg];
      const float vv[4] = {v.x, v.y, v.z, v.w};
      const float ww[4] = {w.x, w.y, w.z, w.w};
      #pragma unroll
      for (int bi = 0; bi < 4; ++bi)
        #pragma unroll
        for (int ji = 0; ji < 4; ++ji)
          acc[bi][ji] = fmaf(vv[bi], ww[ji], acc[bi][ji]);
    }
  }

  // store PA[sel][b][4jg..4jg+3] (f4, coalesced across jg)
  #pragma unroll
  for (int bi = 0; bi < 4; ++bi) {
    const int b = b0 + 4 * bg + bi;
    if (b < B) {
      float4 o = make_float4(acc[bi][0], acc[bi][1], acc[bi][2], acc[bi][3]);
      *(float4*)(PAG + ((size_t)sel * B + b) * 128 + 4 * jg) = o;
    }
  }
  // store V[sel][b][0..99]
  {
    const int bl = tid >> 3, strip = tid & 7;
    const int b = b0 + bl;
    if (b < B) {
      float* dst = VG + ((size_t)sel * B + b) * KDIM;
      for (int k = strip; k < KDIM; k += 8) dst[k] = VT[k][bl];
    }
  }
}

// ---------------- kernel 3: barrier-free per-wave MFMA chain ----------------
// 512 threads = 8 waves; wave wv: net = wv>>2, quarter q = wv&3 (rows 25q..25q+24).
__global__ void __launch_bounds__(512, 4) mlp_kernel(
    const float* __restrict__ VG, const float* __restrict__ PAG,
    const float* __restrict__ tail,
    const float* __restrict__ n1b5, const float* __restrict__ n2b5,
    const __bf16* __restrict__ wfrag, float* __restrict__ out, int B)
{
  __shared__ __align__(16) char smem[SM_BYTES];
  float* sm = (float*)smem;
  const int tid  = threadIdx.x;
  const int lane = tid & 63;
  const int wv   = tid >> 6;
  const int g    = lane >> 4;
  const int c16  = lane & 15;
  const int b    = blockIdx.x;

  // ---- phase 0: coalesced loads of V, PA, biases
  if (tid < 400) sm[L_VEC + tid] = VG[((size_t)(tid / 100) * B + b) * KDIM + (tid % 100)];
  sm[L_PA + tid] = PAG[((size_t)(tid >> 7) * B + b) * 128 + (tid & 127)];
  sm[L_B1 + tid] = tail[tid];    // 512 floats == L_B1..L_W5 exactly
  __syncthreads();

  // ---- per-wave independent MFMA chain
  const int net = wv >> 2;
  const int q   = wv & 3;
  const int r0  = 25 * q;
  const int vA  = net ? (L_VEC + 0)   : (L_VEC + 200);  // net1: sums, net0: scores
  const int vB  = net ? (L_VEC + 100) : (L_VEC + 300);
  const int pAo = L_PA + net * 256;
  const int pBo = pAo + 128;
  __bf16* h2t = (__bf16*)(smem + H2T_BYTE + wv * H2T_WBYTES);  // [16][72]
  __bf16* h3t = (__bf16*)(smem + H3T_BYTE + wv * H3T_WBYTES);  // [16][40]
  const bf16x8* WF = (const bf16x8*)wfrag;
  const int fb = net * 21;
  const float b5v = net ? n2b5[0] : n1b5[0];

  float sAr[2], sBr[2];
  #pragma unroll
  for (int m = 0; m < 2; ++m) {
    const int row = r0 + 16 * m + c16;
    const int rr = row < KDIM ? row : (KDIM - 1);   // clamp; pad rows filtered at write
    sAr[m] = sm[vA + rr]; sBr[m] = sm[vB + rr];
  }

  // ---- layer 2: acc2[m][n], h1 generated in-register
  f32x4 acc2[2][4];
  #pragma unroll
  for (int m = 0; m < 2; ++m)
    #pragma unroll
    for (int n = 0; n < 4; ++n) acc2[m][n] = (f32x4){0.f, 0.f, 0.f, 0.f};

  #pragma unroll
  for (int k = 0; k < 4; ++k) {
    bf16x8 bw[4];
    #pragma unroll
    for (int n = 0; n < 4; ++n) bw[n] = WF[(size_t)(fb + k * 4 + n) * 64 + lane];
    const int jb = 32 * k + 8 * g;
    float paf[8], pbf[8], b1f[8];
    #pragma unroll
    for (int i = 0; i < 8; ++i) {
      paf[i] = sm[pAo + jb + i];
      pbf[i] = sm[pBo + jb + i];
      b1f[i] = sm[L_B1 + net * 128 + jb + i];
    }
    #pragma unroll
    for (int m = 0; m < 2; ++m) {
      bf16x8 a;
      #pragma unroll
      for (int i = 0; i < 8; ++i)
        a[i] = (__bf16)fmaxf(fmaf(sAr[m], paf[i], fmaf(sBr[m], pbf[i], b1f[i])), 0.f);
      #pragma unroll
      for (int n = 0; n < 4; ++n)
        acc2[m][n] = __builtin_amdgcn_mfma_f32_16x16x32_bf16(a, bw[n], acc2[m][n], 0, 0, 0);
    }
  }

  // ---- layer 3/4/5 weights + scalars
  bf16x8 W3f[2][2];
  #pragma unroll
  for (int k = 0; k < 2; ++k)
    #pragma unroll
    for (int n = 0; n < 2; ++n)
      W3f[k][n] = WF[(size_t)(fb + 16 + k * 2 + n) * 64 + lane];
  const bf16x8 W4f = WF[(size_t)(fb + 20) * 64 + lane];
  const float b4v = sm[L_B4 + net * 16 + c16];
  const float w5v = sm[L_W5 + net * 16 + c16];

  // ---- m-chunked tail: per 16-row chunk, reuse small h2t/h3t buffers
  #pragma unroll
  for (int mm = 0; mm < 2; ++mm) {
    // h2 epilogue (chunk mm): local rows 4g+r
    #pragma unroll
    for (int n = 0; n < 4; ++n) {
      const float b2v = sm[L_B2 + net * 64 + 16 * n + c16];
      #pragma unroll
      for (int r = 0; r < 4; ++r)
        h2t[(4 * g + r) * 72 + 16 * n + c16] = (__bf16)fmaxf(acc2[mm][n][r] + b2v, 0.f);
    }
    asm volatile("s_waitcnt lgkmcnt(0)" ::: "memory");
    __builtin_amdgcn_sched_barrier(0);

    // layer 3 (chunk mm)
    f32x4 acc3[2];
    #pragma unroll
    for (int n = 0; n < 2; ++n) acc3[n] = (f32x4){0.f, 0.f, 0.f, 0.f};
    #pragma unroll
    for (int k = 0; k < 2; ++k) {
      const bf16x8 a = *(const bf16x8*)(h2t + c16 * 72 + 32 * k + 8 * g);
      #pragma unroll
      for (int n = 0; n < 2; ++n)
        acc3[n] = __builtin_amdgcn_mfma_f32_16x16x32_bf16(a, W3f[k][n], acc3[n], 0, 0, 0);
    }
    #pragma unroll
    for (int n = 0; n < 2; ++n) {
      const float b3v = sm[L_B3 + net * 32 + 16 * n + c16];
      #pragma unroll
      for (int r = 0; r < 4; ++r)
        h3t[(4 * g + r) * 40 + 16 * n + c16] = (__bf16)fmaxf(acc3[n][r] + b3v, 0.f);
    }
    asm volatile("s_waitcnt lgkmcnt(0)" ::: "memory");
    __builtin_amdgcn_sched_barrier(0);

    // layer 4 + 5 + per-row reduce (chunk mm)
    {
      const bf16x8 a = *(const bf16x8*)(h3t + c16 * 40 + 8 * g);
      const f32x4 z = {0.f, 0.f, 0.f, 0.f};
      const f32x4 acc4 = __builtin_amdgcn_mfma_f32_16x16x32_bf16(a, W4f, z, 0, 0, 0);
      #pragma unroll
      for (int r = 0; r < 4; ++r) {
        float v = fmaxf(acc4[r] + b4v, 0.f) * w5v;   // col pads contribute 0
        v += __shfl_xor(v, 1); v += __shfl_xor(v, 2);
        v += __shfl_xor(v, 4); v += __shfl_xor(v, 8);
        const int lrow = 16 * mm + 4 * g + r;
        if (c16 == 0 && lrow < 25)
          sm[L_C + net * 128 + r0 + lrow] = v + b5v;
      }
    }
  }
  __syncthreads();

  // ---- final: sum rows 0..99 of both nets -> sigmoid(mean)
  float v = 0.f;
  if (tid < KDIM) v = sm[L_C + tid] + sm[L_C + 128 + tid];
  if (tid < 128) {
    #pragma unroll
    for (int d = 1; d < 64; d <<= 1) v += __shfl_xor(v, d);
    if ((tid & 63) == 0) sm[tid >> 6] = v;
  }
  __syncthreads();
  if (tid == 0) out[b] = 1.f / (1.f + expf(-0.01f * (sm[0] + sm[1])));
}

extern "C" void kernel_launch(void* const* d_in, const int* in_sizes, int n_in,
                              void* d_out, int out_size, void* d_ws, size_t ws_size,
                              hipStream_t stream) {
  const int*   user_idxs = (const int*)d_in[0];
  const int*   item_idxs = (const int*)d_in[1];
  const int*   uidx_t    = (const int*)d_in[2];
  const int*   iidx_t    = (const int*)d_in[3];
  const float* uscr      = (const float*)d_in[4];
  const float* iscr      = (const float*)d_in[5];
  const float* uemb      = (const float*)d_in[6];
  const float* iemb      = (const float*)d_in[7];

  const int B  = in_sizes[0];
  const int NU = in_sizes[6] / DDIM;
  const int NI = in_sizes[7] / DDIM;

  Weights N1 { (const float*)d_in[8],  (const float*)d_in[9],
               (const float*)d_in[10], (const float*)d_in[11],
               (const float*)d_in[12], (const float*)d_in[13],
               (const float*)d_in[14], (const float*)d_in[15],
               (const float*)d_in[16], (const float*)d_in[17] };
  Weights N2 { (const float*)d_in[18], (const float*)d_in[19],
               (const float*)d_in[20], (const float*)d_in[21],
               (const float*)d_in[22], (const float*)d_in[23],
               (const float*)d_in[24], (const float*)d_in[25],
               (const float*)d_in[26], (const float*)d_in[27] };

  // workspace layout
  char* ws = (char*)d_ws;
  float* u_rowsum = (float*)ws;
  float* i_rowsum = u_rowsum + NU;
  size_t off = (((size_t)(NU + NI) * 4 + 1023) & ~(size_t)1023);
  __bf16* wfrag = (__bf16*)(ws + off);                 // 42*512 bf16
  float*  tail  = (float*)(wfrag + (size_t)42 * 512);  // 512 f32
  off += (((size_t)42 * 512 * 2 + 512 * 4 + 1023) & ~(size_t)1023);
  float* VG  = (float*)(ws + off);                     // [4][B][100]
  off += (size_t)4 * B * KDIM * 4;
  float* PAG = (float*)(ws + off);                     // [4][B][128]

  float* out = (float*)d_out;

  prep_kernel<<<1024, 256, 0, stream>>>(uemb, iemb, u_rowsum, i_rowsum, NU, NI, N1, N2, wfrag, tail);
  const int nbt = (B + 31) / 32;
  proj_kernel<<<nbt * 4, 256, 0, stream>>>(user_idxs, item_idxs, uidx_t, iidx_t,
                                           uscr, iscr, u_rowsum, i_rowsum,
                                           N1.w1, N2.w1, VG, PAG, B);
  mlp_kernel<<<B, 512, 0, stream>>>(VG, PAG, tail, N1.b5, N2.b5, wfrag, out, B);
}

// Round 9
// 82.441 us; speedup vs baseline: 1.1972x; 1.0513x over previous
//
#include <hip/hip_runtime.h>
#include <math.h>

#define KDIM 100
#define DDIM 64

typedef __bf16 bf16x8 __attribute__((ext_vector_type(8)));
typedef float  f32x4  __attribute__((ext_vector_type(4)));
typedef float  f32x2  __attribute__((ext_vector_type(2)));
typedef unsigned int u32;
typedef u32 u32x2 __attribute__((ext_vector_type(2)));

struct Weights {
  const float *w1, *b1, *w2, *b2, *w3, *b3, *w4, *b4, *w5, *b5;
};

__device__ __forceinline__ f32x2 pkfma(f32x2 a, f32x2 b, f32x2 c) {
  f32x2 d;
  asm("v_pk_fma_f32 %0, %1, %2, %3" : "=v"(d) : "v"(a), "v"(b), "v"(c));
  return d;
}
__device__ __forceinline__ u32 cvtpk(float lo, float hi) {
  u32 d;
  asm("v_cvt_pk_bf16_f32 %0, %1, %2" : "=v"(d) : "v"(lo), "v"(hi));
  return d;
}
union FragU { u32 u[4]; bf16x8 v; };

// ---------------- mlp LDS layout ----------------
// floats: L_VEC [4][100] | L_PA [4][128] | L_TAIL [512] | L_C [2][128]
constexpr int L_VEC  = 0;
constexpr int L_PA   = 400;
constexpr int L_TAIL = 912;   // b1[2][128]@0 b2[2][64]@256 b3[2][32]@384 b4[2][16]@448 w5[2][16]@480
constexpr int L_C    = 1424;
constexpr int SM_F   = 1680;             // 6720 B
constexpr int WF_BYTE  = SM_F * 4;       // 6720, 2*21*64*16 = 43008 B of weight frags
constexpr int H2T_BYTE = WF_BYTE + 43008;        // 49728; 8 waves x [16][72] bf16 (2304 B)
constexpr int H3T_BYTE = H2T_BYTE + 8 * 2304;    // 68160; 8 waves x [16][40] bf16 (1280 B)
constexpr int SM_BYTES = H3T_BYTE + 8 * 1280;    // 78400 B -> 2 blocks/CU

// ---------------- kernel 1: rowsums + transposed A-frag pack + bias tail ----------------
// wfrag: [net(2)][frag f(21)][lane(64)][8 bf16].
// f 0-15:  W2^T A-frag (mt=f>>2, ks=f&3): elem i = w2[32ks+8g+i][16mt+c16]
// f 16-19: W3^T (mt=(f-16)>>1, ks=(f-16)&1): elem i = w3[32ks+8g+i][16mt+c16]
// f 20:    W4^T: elem i = w4[8g+i][c16]
__global__ void prep_kernel(const float* __restrict__ user_emb,
                            const float* __restrict__ item_emb,
                            float* __restrict__ u_rowsum,
                            float* __restrict__ i_rowsum,
                            int NU, int NI, Weights N1, Weights N2,
                            __bf16* __restrict__ wfrag, float* __restrict__ tail) {
  const int tid  = threadIdx.x;
  const int lane = tid & 63;
  const int g = lane >> 4, c16 = lane & 15;
  const int gw = (blockIdx.x * blockDim.x + tid) >> 6;

  if (gw < 42) {
    const int net = gw / 21, f = gw % 21;
    const Weights W = net ? N2 : N1;
    bf16x8 v;
    if (f < 16) {
      const int mt = f >> 2, ks = f & 3;
      #pragma unroll
      for (int i = 0; i < 8; ++i) {
        const int k = 32 * ks + 8 * g + i, m = 16 * mt + c16;
        v[i] = (__bf16)((k < 100 && m < 50) ? W.w2[k * 50 + m] : 0.f);
      }
    } else if (f < 20) {
      const int mt = (f - 16) >> 1, ks = (f - 16) & 1;
      #pragma unroll
      for (int i = 0; i < 8; ++i) {
        const int k = 32 * ks + 8 * g + i, m = 16 * mt + c16;
        v[i] = (__bf16)((k < 50 && m < 25) ? W.w3[k * 25 + m] : 0.f);
      }
    } else {
      #pragma unroll
      for (int i = 0; i < 8; ++i) {
        const int k = 8 * g + i, m = c16;
        v[i] = (__bf16)((k < 25 && m < 12) ? W.w4[k * 12 + m] : 0.f);
      }
    }
    *(bf16x8*)(wfrag + (size_t)gw * 512 + lane * 8) = v;
  }

  if (blockIdx.x == 0) {
    for (int e = tid; e < 512; e += 256) {
      float v;
      if (e < 256)      { const int j = e & 127; const Weights W = (e & 128) ? N2 : N1; v = (j < 100) ? W.b1[j] : 0.f; }
      else if (e < 384) { const int t = e - 256; const int j = t & 63; const Weights W = (t & 64) ? N2 : N1; v = (j < 50) ? W.b2[j] : 0.f; }
      else if (e < 448) { const int t = e - 384; const int j = t & 31; const Weights W = (t & 32) ? N2 : N1; v = (j < 25) ? W.b3[j] : 0.f; }
      else if (e < 480) { const int t = e - 448; const int j = t & 15; const Weights W = (t & 16) ? N2 : N1; v = (j < 12) ? W.b4[j] : 0.f; }
      else              { const int t = e - 480; const int j = t & 15; const Weights W = (t & 16) ? N2 : N1; v = (j < 12) ? W.w5[j] : 0.f; }
      tail[e] = v;
    }
  }

  const int NR = NU + NI;
  const int chunk = lane & 15, lrow = lane >> 4;
  const int nwave = (gridDim.x * blockDim.x) >> 6;
  for (int base = gw * 4; base < NR; base += nwave * 4) {
    const int r = base + lrow;
    float s = 0.f;
    if (r < NR) {
      const float* src = (r < NU) ? (user_emb + (size_t)r * DDIM)
                                  : (item_emb + (size_t)(r - NU) * DDIM);
      const float4 v4 = ((const float4*)src)[chunk];
      s = v4.x + v4.y + v4.z + v4.w;
    }
    s += __shfl_xor(s, 1); s += __shfl_xor(s, 2);
    s += __shfl_xor(s, 4); s += __shfl_xor(s, 8);
    if (chunk == 0 && r < NR) {
      if (r < NU) u_rowsum[r] = s; else i_rowsum[r - NU] = s;
    }
  }
}

// ---------------- kernel 2: batched layer-1 projections (TILE_B = 16) ----------------
__global__ void __launch_bounds__(256) proj_kernel(
    const int* __restrict__ user_idxs, const int* __restrict__ item_idxs,
    const int* __restrict__ uidx_t, const int* __restrict__ iidx_t,
    const float* __restrict__ uscr, const float* __restrict__ iscr,
    const float* __restrict__ u_rowsum, const float* __restrict__ i_rowsum,
    const float* __restrict__ n1w1, const float* __restrict__ n2w1,
    float* __restrict__ VG, float* __restrict__ PAG, int B)
{
  __shared__ float VT[100][20];     // [k][b_local], stride 20 (even -> 8B-aligned f32x2)
  __shared__ float W1S[50][128];    // staged w1 k-half, cols 100..127 zero
  __shared__ int sidx[16];
  const int tid = threadIdx.x;
  const int sel = blockIdx.x & 3;
  const int b0  = (blockIdx.x >> 2) * 16;

  if (tid < 16) {
    const int b = b0 + tid;
    const int bb = (b < B) ? b : (B - 1);
    sidx[tid] = (sel & 1) ? item_idxs[bb] : user_idxs[bb];
  }
  __syncthreads();

  // gather V-tile: 16 threads per batch
  {
    const int bl = tid >> 4, strip = tid & 15;
    const size_t row = (size_t)sidx[bl] * KDIM;
    if (sel == 0) {
      for (int k = strip; k < KDIM; k += 16) VT[k][bl] = u_rowsum[uidx_t[row + k]];
    } else if (sel == 1) {
      for (int k = strip; k < KDIM; k += 16) VT[k][bl] = i_rowsum[iidx_t[row + k]];
    } else if (sel == 2) {
      for (int k = strip; k < KDIM; k += 16) VT[k][bl] = uscr[row + k];
    } else {
      for (int k = strip; k < KDIM; k += 16) VT[k][bl] = iscr[row + k];
    }
  }

  const float* w1 = (sel < 2) ? n1w1 : n2w1;
  const int rb = (sel & 1) * KDIM;
  const int jg = tid & 31, bg = tid >> 5;   // j0 = 4*jg (128 j), batches 2*bg..2*bg+1
  float acc[2][4];
  #pragma unroll
  for (int bi = 0; bi < 2; ++bi)
    #pragma unroll
    for (int ji = 0; ji < 4; ++ji) acc[bi][ji] = 0.f;

  for (int kh = 0; kh < 2; ++kh) {
    __syncthreads();
    for (int e = tid; e < 1600; e += 256) {
      const int k = e >> 5, s = e & 31;
      float4 v;
      if (s < 25) v = ((const float4*)(w1 + (size_t)(rb + kh * 50 + k) * KDIM))[s];
      else        v = make_float4(0.f, 0.f, 0.f, 0.f);
      *(float4*)&W1S[k][4 * s] = v;
    }
    __syncthreads();
    #pragma unroll 2
    for (int k = 0; k < 50; ++k) {
      const f32x2 v = *(const f32x2*)&VT[kh * 50 + k][2 * bg];
      const float4 w = *(const float4*)&W1S[k][4 * jg];
      const float ww[4] = {w.x, w.y, w.z, w.w};
      #pragma unroll
      for (int ji = 0; ji < 4; ++ji) {
        acc[0][ji] = fmaf(v[0], ww[ji], acc[0][ji]);
        acc[1][ji] = fmaf(v[1], ww[ji], acc[1][ji]);
      }
    }
  }

  #pragma unroll
  for (int bi = 0; bi < 2; ++bi) {
    const int b = b0 + 2 * bg + bi;
    if (b < B) {
      float4 o = make_float4(acc[bi][0], acc[bi][1], acc[bi][2], acc[bi][3]);
      *(float4*)(PAG + ((size_t)sel * B + b) * 128 + 4 * jg) = o;
    }
  }
  {
    const int bl = tid >> 4, strip = tid & 15;
    const int b = b0 + bl;
    if (b < B) {
      float* dst = VG + ((size_t)sel * B + b) * KDIM;
      for (int k = strip; k < KDIM; k += 16) dst[k] = VT[k][bl];
    }
  }
}

// ---------------- kernel 3: swapped-operand barrier-free MFMA chain ----------------
// 512 threads = 8 waves; wave wv: net = wv>>2, quarter q = wv&3 (rows 25q..25q+24).
// All MFMAs: A = W^T frag (from LDS), B = activation frag; C: col(c16)=batch-row,
// rows(4g+r)=output-col -> vectorized b64 epilogue writes.
__global__ void __launch_bounds__(512, 4) mlp_kernel(
    const float* __restrict__ VG, const float* __restrict__ PAG,
    const float* __restrict__ tail,
    const float* __restrict__ n1b5, const float* __restrict__ n2b5,
    const __bf16* __restrict__ wfrag, float* __restrict__ out, int B)
{
  __shared__ __align__(16) char smem[SM_BYTES];
  float* sm = (float*)smem;
  const int tid  = threadIdx.x;
  const int lane = tid & 63;
  const int wv   = tid >> 6;
  const int g    = lane >> 4;
  const int c16  = lane & 15;
  const int b    = blockIdx.x;

  // ---- phase 0: stage weight frags (43008 B) + PA + tail + V
  {
    const float4* src = (const float4*)wfrag;
    float4* dst = (float4*)(smem + WF_BYTE);
    for (int e = tid; e < 2688; e += 512) dst[e] = src[e];
  }
  if (tid < 128) {
    const int sel = tid >> 5, s = tid & 31;
    *(float4*)&sm[L_PA + sel * 128 + 4 * s] =
        *(const float4*)(PAG + ((size_t)sel * B + b) * 128 + 4 * s);
  } else if (tid < 256) {
    const int t = tid - 128;
    *(float4*)&sm[L_TAIL + 4 * t] = *(const float4*)(tail + 4 * t);
  } else if (tid < 456) {
    const int e = tid - 256;
    const int sel = e / 50, r = e % 50;
    *(f32x2*)&sm[L_VEC + sel * 100 + 2 * r] =
        *(const f32x2*)(VG + ((size_t)sel * B + b) * KDIM + 2 * r);
  }
  __syncthreads();

  const int net = wv >> 2;
  const int q   = wv & 3;
  const int r0  = 25 * q;
  const int vA  = net ? (L_VEC + 0)   : (L_VEC + 200);  // net1: sums, net0: scores
  const int vB  = net ? (L_VEC + 100) : (L_VEC + 300);
  const int pAo = L_PA + net * 256;
  const int pBo = pAo + 128;
  const char* wfb = smem + WF_BYTE + net * 21 * 1024;   // frag f at +f*1024+lane*16
  char* h2t = smem + H2T_BYTE + wv * 2304;  // [16][72] bf16, row pitch 144 B
  char* h3t = smem + H3T_BYTE + wv * 1280;  // [16][40] bf16, row pitch 80 B
  const float b5v = net ? n2b5[0] : n1b5[0];

  f32x2 sA2[2], sB2[2];
  #pragma unroll
  for (int c = 0; c < 2; ++c) {
    const int row = r0 + 16 * c + c16;
    const int rr = row < KDIM ? row : (KDIM - 1);
    const float a = sm[vA + rr], bb = sm[vB + rr];
    sA2[c] = (f32x2){a, a}; sB2[c] = (f32x2){bb, bb};
  }

  // ---- layer 2: acc2[chunk][mt] += mfma(W2T[mt][ks], h1frag[chunk][ks])
  f32x4 acc2[2][4];
  #pragma unroll
  for (int c = 0; c < 2; ++c)
    #pragma unroll
    for (int mt = 0; mt < 4; ++mt) acc2[c][mt] = (f32x4){0.f, 0.f, 0.f, 0.f};

  #pragma unroll
  for (int ks = 0; ks < 4; ++ks) {
    const int jb = 32 * ks + 8 * g;
    const f32x4 pa0 = *(const f32x4*)&sm[pAo + jb];
    const f32x4 pa1 = *(const f32x4*)&sm[pAo + jb + 4];
    const f32x4 pb0 = *(const f32x4*)&sm[pBo + jb];
    const f32x4 pb1 = *(const f32x4*)&sm[pBo + jb + 4];
    const f32x4 b10 = *(const f32x4*)&sm[L_TAIL + net * 128 + jb];
    const f32x4 b11 = *(const f32x4*)&sm[L_TAIL + net * 128 + jb + 4];
    bf16x8 hb[2];
    #pragma unroll
    for (int c = 0; c < 2; ++c) {
      FragU fu;
      f32x2 t;
      t = pkfma(sB2[c], (f32x2){pb0[0], pb0[1]}, (f32x2){b10[0], b10[1]});
      t = pkfma(sA2[c], (f32x2){pa0[0], pa0[1]}, t);
      fu.u[0] = cvtpk(fmaxf(t[0], 0.f), fmaxf(t[1], 0.f));
      t = pkfma(sB2[c], (f32x2){pb0[2], pb0[3]}, (f32x2){b10[2], b10[3]});
      t = pkfma(sA2[c], (f32x2){pa0[2], pa0[3]}, t);
      fu.u[1] = cvtpk(fmaxf(t[0], 0.f), fmaxf(t[1], 0.f));
      t = pkfma(sB2[c], (f32x2){pb1[0], pb1[1]}, (f32x2){b11[0], b11[1]});
      t = pkfma(sA2[c], (f32x2){pa1[0], pa1[1]}, t);
      fu.u[2] = cvtpk(fmaxf(t[0], 0.f), fmaxf(t[1], 0.f));
      t = pkfma(sB2[c], (f32x2){pb1[2], pb1[3]}, (f32x2){b11[2], b11[3]});
      t = pkfma(sA2[c], (f32x2){pa1[2], pa1[3]}, t);
      fu.u[3] = cvtpk(fmaxf(t[0], 0.f), fmaxf(t[1], 0.f));
      hb[c] = fu.v;
    }
    #pragma unroll
    for (int mt = 0; mt < 4; ++mt) {
      const bf16x8 a = *(const bf16x8*)(wfb + (mt * 4 + ks) * 1024 + lane * 16);
      acc2[0][mt] = __builtin_amdgcn_mfma_f32_16x16x32_bf16(a, hb[0], acc2[0][mt], 0, 0, 0);
      acc2[1][mt] = __builtin_amdgcn_mfma_f32_16x16x32_bf16(a, hb[1], acc2[1][mt], 0, 0, 0);
    }
  }

  // ---- per-chunk: h2 epilogue -> L3 -> h3 epilogue -> L4+L5
  #pragma unroll
  for (int c = 0; c < 2; ++c) {
    #pragma unroll
    for (int mt = 0; mt < 4; ++mt) {
      const f32x4 b2v = *(const f32x4*)&sm[L_TAIL + 256 + net * 64 + 16 * mt + 4 * g];
      const f32x4 x = acc2[c][mt];
      u32x2 w2o = { cvtpk(fmaxf(x[0] + b2v[0], 0.f), fmaxf(x[1] + b2v[1], 0.f)),
                    cvtpk(fmaxf(x[2] + b2v[2], 0.f), fmaxf(x[3] + b2v[3], 0.f)) };
      *(u32x2*)(h2t + c16 * 144 + (16 * mt + 4 * g) * 2) = w2o;
    }
    asm volatile("s_waitcnt lgkmcnt(0)" ::: "memory");
    __builtin_amdgcn_sched_barrier(0);

    // layer 3: h3^T = W3^T @ h2^T
    f32x4 acc3[2];
    #pragma unroll
    for (int mt = 0; mt < 2; ++mt) acc3[mt] = (f32x4){0.f, 0.f, 0.f, 0.f};
    #pragma unroll
    for (int ks = 0; ks < 2; ++ks) {
      const bf16x8 hbf = *(const bf16x8*)(h2t + c16 * 144 + (32 * ks + 8 * g) * 2);
      #pragma unroll
      for (int mt = 0; mt < 2; ++mt) {
        const bf16x8 a = *(const bf16x8*)(wfb + (16 + mt * 2 + ks) * 1024 + lane * 16);
        acc3[mt] = __builtin_amdgcn_mfma_f32_16x16x32_bf16(a, hbf, acc3[mt], 0, 0, 0);
      }
    }
    #pragma unroll
    for (int mt = 0; mt < 2; ++mt) {
      const f32x4 b3v = *(const f32x4*)&sm[L_TAIL + 384 + net * 32 + 16 * mt + 4 * g];
      const f32x4 x = acc3[mt];
      u32x2 w3o = { cvtpk(fmaxf(x[0] + b3v[0], 0.f), fmaxf(x[1] + b3v[1], 0.f)),
                    cvtpk(fmaxf(x[2] + b3v[2], 0.f), fmaxf(x[3] + b3v[3], 0.f)) };
      *(u32x2*)(h3t + c16 * 80 + (16 * mt + 4 * g) * 2) = w3o;
    }
    asm volatile("s_waitcnt lgkmcnt(0)" ::: "memory");
    __builtin_amdgcn_sched_barrier(0);

    // layer 4 + 5 + per-row reduce
    {
      const bf16x8 hbf = *(const bf16x8*)(h3t + c16 * 80 + 16 * g);
      const bf16x8 a = *(const bf16x8*)(wfb + 20 * 1024 + lane * 16);
      const f32x4 z = {0.f, 0.f, 0.f, 0.f};
      const f32x4 acc4 = __builtin_amdgcn_mfma_f32_16x16x32_bf16(a, hbf, z, 0, 0, 0);
      const f32x4 b4v = *(const f32x4*)&sm[L_TAIL + 448 + net * 16 + 4 * g];
      const f32x4 w5v = *(const f32x4*)&sm[L_TAIL + 480 + net * 16 + 4 * g];
      float v = 0.f;
      #pragma unroll
      for (int r = 0; r < 4; ++r)
        v = fmaf(fmaxf(acc4[r] + b4v[r], 0.f), w5v[r], v);   // pad cols: b4=w5=0
      v += __shfl_xor(v, 16); v += __shfl_xor(v, 32);
      const int lr = 16 * c + c16;
      if (g == 0 && lr < 25)
        sm[L_C + net * 128 + r0 + lr] = v + b5v;
    }
    asm volatile("s_waitcnt lgkmcnt(0)" ::: "memory");   // WAR guard before next chunk
    __builtin_amdgcn_sched_barrier(0);
  }
  __syncthreads();

  // ---- final: sum rows 0..99 of both nets -> sigmoid(mean)
  float v = 0.f;
  if (tid < KDIM) v = sm[L_C + tid] + sm[L_C + 128 + tid];
  if (tid < 128) {
    #pragma unroll
    for (int d = 1; d < 64; d <<= 1) v += __shfl_xor(v, d);
    if ((tid & 63) == 0) sm[tid >> 6] = v;
  }
  __syncthreads();
  if (tid == 0) out[b] = 1.f / (1.f + expf(-0.01f * (sm[0] + sm[1])));
}

extern "C" void kernel_launch(void* const* d_in, const int* in_sizes, int n_in,
                              void* d_out, int out_size, void* d_ws, size_t ws_size,
                              hipStream_t stream) {
  const int*   user_idxs = (const int*)d_in[0];
  const int*   item_idxs = (const int*)d_in[1];
  const int*   uidx_t    = (const int*)d_in[2];
  const int*   iidx_t    = (const int*)d_in[3];
  const float* uscr      = (const float*)d_in[4];
  const float* iscr      = (const float*)d_in[5];
  const float* uemb      = (const float*)d_in[6];
  const float* iemb      = (const float*)d_in[7];

  const int B  = in_sizes[0];
  const int NU = in_sizes[6] / DDIM;
  const int NI = in_sizes[7] / DDIM;

  Weights N1 { (const float*)d_in[8],  (const float*)d_in[9],
               (const float*)d_in[10], (const float*)d_in[11],
               (const float*)d_in[12], (const float*)d_in[13],
               (const float*)d_in[14], (const float*)d_in[15],
               (const float*)d_in[16], (const float*)d_in[17] };
  Weights N2 { (const float*)d_in[18], (const float*)d_in[19],
               (const float*)d_in[20], (const float*)d_in[21],
               (const float*)d_in[22], (const float*)d_in[23],
               (const float*)d_in[24], (const float*)d_in[25],
               (const float*)d_in[26], (const float*)d_in[27] };

  char* ws = (char*)d_ws;
  float* u_rowsum = (float*)ws;
  float* i_rowsum = u_rowsum + NU;
  size_t off = (((size_t)(NU + NI) * 4 + 1023) & ~(size_t)1023);
  __bf16* wfrag = (__bf16*)(ws + off);                 // 42*512 bf16 = 43008 B
  float*  tail  = (float*)(wfrag + (size_t)42 * 512);  // 512 f32
  off += (((size_t)42 * 512 * 2 + 512 * 4 + 1023) & ~(size_t)1023);
  float* VG  = (float*)(ws + off);                     // [4][B][100]
  off += (size_t)4 * B * KDIM * 4;
  float* PAG = (float*)(ws + off);                     // [4][B][128]

  float* out = (float*)d_out;

  prep_kernel<<<1024, 256, 0, stream>>>(uemb, iemb, u_rowsum, i_rowsum, NU, NI, N1, N2, wfrag, tail);
  const int nbt = (B + 15) / 16;
  proj_kernel<<<nbt * 4, 256, 0, stream>>>(user_idxs, item_idxs, uidx_t, iidx_t,
                                           uscr, iscr, u_rowsum, i_rowsum,
                                           N1.w1, N2.w1, VG, PAG, B);
  mlp_kernel<<<B, 512, 0, stream>>>(VG, PAG, tail, N1.b5, N2.b5, wfrag, out, B);
}

// Round 11
// 79.266 us; speedup vs baseline: 1.2452x; 1.0401x over previous
//
#include <hip/hip_runtime.h>
#include <math.h>

#define KDIM 100
#define DDIM 64

typedef __bf16 bf16x8 __attribute__((ext_vector_type(8)));
typedef float  f32x4  __attribute__((ext_vector_type(4)));
typedef float  f32x2  __attribute__((ext_vector_type(2)));
typedef unsigned int u32;
typedef u32 u32x2 __attribute__((ext_vector_type(2)));

struct Weights {
  const float *w1, *b1, *w2, *b2, *w3, *b3, *w4, *b4, *w5, *b5;
};

// ---------------- mlp LDS layout ----------------
// floats: L_VEC [4][100] | L_PA [4][128] | L_TAIL [512] | L_C [2][128]
constexpr int L_VEC  = 0;
constexpr int L_PA   = 400;
constexpr int L_TAIL = 912;   // b1[2][128]@0 b2[2][64]@256 b3[2][32]@384 b4[2][16]@448 w5[2][16]@480
constexpr int L_C    = 1424;
constexpr int SM_F   = 1680;             // 6720 B
constexpr int WF_BYTE  = SM_F * 4;       // 6720; 2*21*64*16 = 43008 B of weight frags
constexpr int H2T_BYTE = WF_BYTE + 43008;        // 49728; 8 waves x 16 rows x 128 B (swizzled)
constexpr int H3T_BYTE = H2T_BYTE + 8 * 2048;    // 66112; 8 waves x 16 rows x 64 B (swizzled)
constexpr int SM_BYTES = H3T_BYTE + 8 * 1024;    // 74304 B -> 2 blocks/CU

// ---------------- kernel 1: rowsums + transposed A-frag pack + bias tail ----------------
// wfrag: [net(2)][frag f(21)][lane(64)][8 bf16].
// f 0-15:  W2^T A-frag (mt=f>>2, ks=f&3): elem i = w2[32ks+8g+i][16mt+c16]
// f 16-19: W3^T (mt=(f-16)>>1, ks=(f-16)&1): elem i = w3[32ks+8g+i][16mt+c16]
// f 20:    W4^T: elem i = w4[8g+i][c16]
__global__ void prep_kernel(const float* __restrict__ user_emb,
                            const float* __restrict__ item_emb,
                            float* __restrict__ u_rowsum,
                            float* __restrict__ i_rowsum,
                            int NU, int NI, Weights N1, Weights N2,
                            __bf16* __restrict__ wfrag, float* __restrict__ tail) {
  const int tid  = threadIdx.x;
  const int lane = tid & 63;
  const int g = lane >> 4, c16 = lane & 15;
  const int gw = (blockIdx.x * blockDim.x + tid) >> 6;

  if (gw < 42) {
    const int net = gw / 21, f = gw % 21;
    const Weights W = net ? N2 : N1;
    bf16x8 v;
    if (f < 16) {
      const int mt = f >> 2, ks = f & 3;
      #pragma unroll
      for (int i = 0; i < 8; ++i) {
        const int k = 32 * ks + 8 * g + i, m = 16 * mt + c16;
        v[i] = (__bf16)((k < 100 && m < 50) ? W.w2[k * 50 + m] : 0.f);
      }
    } else if (f < 20) {
      const int mt = (f - 16) >> 1, ks = (f - 16) & 1;
      #pragma unroll
      for (int i = 0; i < 8; ++i) {
        const int k = 32 * ks + 8 * g + i, m = 16 * mt + c16;
        v[i] = (__bf16)((k < 50 && m < 25) ? W.w3[k * 25 + m] : 0.f);
      }
    } else {
      #pragma unroll
      for (int i = 0; i < 8; ++i) {
        const int k = 8 * g + i, m = c16;
        v[i] = (__bf16)((k < 25 && m < 12) ? W.w4[k * 12 + m] : 0.f);
      }
    }
    *(bf16x8*)(wfrag + (size_t)gw * 512 + lane * 8) = v;
  }

  if (blockIdx.x == 0) {
    for (int e = tid; e < 512; e += 256) {
      float v;
      if (e < 256)      { const int j = e & 127; const Weights W = (e & 128) ? N2 : N1; v = (j < 100) ? W.b1[j] : 0.f; }
      else if (e < 384) { const int t = e - 256; const int j = t & 63; const Weights W = (t & 64) ? N2 : N1; v = (j < 50) ? W.b2[j] : 0.f; }
      else if (e < 448) { const int t = e - 384; const int j = t & 31; const Weights W = (t & 32) ? N2 : N1; v = (j < 25) ? W.b3[j] : 0.f; }
      else if (e < 480) { const int t = e - 448; const int j = t & 15; const Weights W = (t & 16) ? N2 : N1; v = (j < 12) ? W.b4[j] : 0.f; }
      else              { const int t = e - 480; const int j = t & 15; const Weights W = (t & 16) ? N2 : N1; v = (j < 12) ? W.w5[j] : 0.f; }
      tail[e] = v;
    }
  }

  const int NR = NU + NI;
  const int chunk = lane & 15, lrow = lane >> 4;
  const int nwave = (gridDim.x * blockDim.x) >> 6;
  for (int base = gw * 4; base < NR; base += nwave * 4) {
    const int r = base + lrow;
    float s = 0.f;
    if (r < NR) {
      const float* src = (r < NU) ? (user_emb + (size_t)r * DDIM)
                                  : (item_emb + (size_t)(r - NU) * DDIM);
      const float4 v4 = ((const float4*)src)[chunk];
      s = v4.x + v4.y + v4.z + v4.w;
    }
    s += __shfl_xor(s, 1); s += __shfl_xor(s, 2);
    s += __shfl_xor(s, 4); s += __shfl_xor(s, 8);
    if (chunk == 0 && r < NR) {
      if (r < NU) u_rowsum[r] = s; else i_rowsum[r - NU] = s;
    }
  }
}

// ---------------- kernel 2: batched layer-1 projections (TILE_B = 16) ----------------
__global__ void __launch_bounds__(256) proj_kernel(
    const int* __restrict__ user_idxs, const int* __restrict__ item_idxs,
    const int* __restrict__ uidx_t, const int* __restrict__ iidx_t,
    const float* __restrict__ uscr, const float* __restrict__ iscr,
    const float* __restrict__ u_rowsum, const float* __restrict__ i_rowsum,
    const float* __restrict__ n1w1, const float* __restrict__ n2w1,
    float* __restrict__ VG, float* __restrict__ PAG, int B)
{
  __shared__ float VT[100][20];     // [k][b_local], stride 20 (even -> 8B-aligned f32x2)
  __shared__ float W1S[50][128];    // staged w1 k-half, cols 100..127 zero
  __shared__ int sidx[16];
  const int tid = threadIdx.x;
  const int sel = blockIdx.x & 3;
  const int b0  = (blockIdx.x >> 2) * 16;

  if (tid < 16) {
    const int b = b0 + tid;
    const int bb = (b < B) ? b : (B - 1);
    sidx[tid] = (sel & 1) ? item_idxs[bb] : user_idxs[bb];
  }
  __syncthreads();

  // gather V-tile: 16 threads per batch
  {
    const int bl = tid >> 4, strip = tid & 15;
    const size_t row = (size_t)sidx[bl] * KDIM;
    if (sel == 0) {
      for (int k = strip; k < KDIM; k += 16) VT[k][bl] = u_rowsum[uidx_t[row + k]];
    } else if (sel == 1) {
      for (int k = strip; k < KDIM; k += 16) VT[k][bl] = i_rowsum[iidx_t[row + k]];
    } else if (sel == 2) {
      for (int k = strip; k < KDIM; k += 16) VT[k][bl] = uscr[row + k];
    } else {
      for (int k = strip; k < KDIM; k += 16) VT[k][bl] = iscr[row + k];
    }
  }

  const float* w1 = (sel < 2) ? n1w1 : n2w1;
  const int rb = (sel & 1) * KDIM;
  const int jg = tid & 31, bg = tid >> 5;   // j0 = 4*jg (128 j), batches 2*bg..2*bg+1
  float acc[2][4];
  #pragma unroll
  for (int bi = 0; bi < 2; ++bi)
    #pragma unroll
    for (int ji = 0; ji < 4; ++ji) acc[bi][ji] = 0.f;

  for (int kh = 0; kh < 2; ++kh) {
    __syncthreads();
    for (int e = tid; e < 1600; e += 256) {
      const int k = e >> 5, s = e & 31;
      float4 v;
      if (s < 25) v = ((const float4*)(w1 + (size_t)(rb + kh * 50 + k) * KDIM))[s];
      else        v = make_float4(0.f, 0.f, 0.f, 0.f);
      *(float4*)&W1S[k][4 * s] = v;
    }
    __syncthreads();
    #pragma unroll 2
    for (int k = 0; k < 50; ++k) {
      const f32x2 v = *(const f32x2*)&VT[kh * 50 + k][2 * bg];
      const float4 w = *(const float4*)&W1S[k][4 * jg];
      const float ww[4] = {w.x, w.y, w.z, w.w};
      #pragma unroll
      for (int ji = 0; ji < 4; ++ji) {
        acc[0][ji] = fmaf(v[0], ww[ji], acc[0][ji]);
        acc[1][ji] = fmaf(v[1], ww[ji], acc[1][ji]);
      }
    }
  }

  #pragma unroll
  for (int bi = 0; bi < 2; ++bi) {
    const int b = b0 + 2 * bg + bi;
    if (b < B) {
      float4 o = make_float4(acc[bi][0], acc[bi][1], acc[bi][2], acc[bi][3]);
      *(float4*)(PAG + ((size_t)sel * B + b) * 128 + 4 * jg) = o;
    }
  }
  {
    const int bl = tid >> 4, strip = tid & 15;
    const int b = b0 + bl;
    if (b < B) {
      float* dst = VG + ((size_t)sel * B + b) * KDIM;
      for (int k = strip; k < KDIM; k += 16) dst[k] = VT[k][bl];
    }
  }
}

// ---------------- kernel 3: swapped-operand barrier-free MFMA chain ----------------
// 512 threads = 8 waves; wave wv: net = wv>>2, quarter q = wv&3 (rows 25q..25q+24).
// All MFMAs: A = W^T frag (LDS), B = activation frag; C rows = out-cols, C cols = batch rows.
// Transpose buffers: XOR-swizzled 16B slots (slot ^= row&7 / row&3), row pitch 128B / 64B.
__global__ void __launch_bounds__(512, 4) mlp_kernel(
    const float* __restrict__ VG, const float* __restrict__ PAG,
    const float* __restrict__ tail,
    const float* __restrict__ n1b5, const float* __restrict__ n2b5,
    const __bf16* __restrict__ wfrag, float* __restrict__ out, int B)
{
  __shared__ __align__(16) char smem[SM_BYTES];
  float* sm = (float*)smem;
  const int tid  = threadIdx.x;
  const int lane = tid & 63;
  const int wv   = tid >> 6;
  const int g    = lane >> 4;
  const int c16  = lane & 15;
  const int b    = blockIdx.x;

  // ---- phase 0: stage weight frags (43008 B) + PA + tail + V
  {
    const float4* src = (const float4*)wfrag;
    float4* dst = (float4*)(smem + WF_BYTE);
    for (int e = tid; e < 2688; e += 512) dst[e] = src[e];
  }
  if (tid < 128) {
    const int sel = tid >> 5, s = tid & 31;
    *(float4*)&sm[L_PA + sel * 128 + 4 * s] =
        *(const float4*)(PAG + ((size_t)sel * B + b) * 128 + 4 * s);
  } else if (tid < 256) {
    const int t = tid - 128;
    *(float4*)&sm[L_TAIL + 4 * t] = *(const float4*)(tail + 4 * t);
  } else if (tid < 456) {
    const int e = tid - 256;
    const int sel = e / 50, r = e % 50;
    *(f32x2*)&sm[L_VEC + sel * 100 + 2 * r] =
        *(const f32x2*)(VG + ((size_t)sel * B + b) * KDIM + 2 * r);
  }
  __syncthreads();

  const int net = wv >> 2;
  const int q   = wv & 3;
  const int r0  = 25 * q;
  const int vA  = net ? (L_VEC + 0)   : (L_VEC + 200);  // net1: sums, net0: scores
  const int vB  = net ? (L_VEC + 100) : (L_VEC + 300);
  const int pAo = L_PA + net * 256;
  const int pBo = pAo + 128;
  const char* wfb = smem + WF_BYTE + net * 21 * 1024;   // frag f at +f*1024+lane*16
  char* h2t = smem + H2T_BYTE + wv * 2048;  // [16 rows][128 B], swizzled
  char* h3t = smem + H3T_BYTE + wv * 1024;  // [16 rows][64 B], swizzled
  const float b5v = net ? n2b5[0] : n1b5[0];
  const int t7 = c16 & 7, t3 = c16 & 3;

  float sAr[2], sBr[2];
  #pragma unroll
  for (int c = 0; c < 2; ++c) {
    const int row = r0 + 16 * c + c16;
    const int rr = row < KDIM ? row : (KDIM - 1);
    sAr[c] = sm[vA + rr]; sBr[c] = sm[vB + rr];
  }

  // ---- layer 2: acc2[chunk][mt] += mfma(W2T[mt][ks], h1frag[chunk][ks])
  f32x4 acc2[2][4];
  #pragma unroll
  for (int c = 0; c < 2; ++c)
    #pragma unroll
    for (int mt = 0; mt < 4; ++mt) acc2[c][mt] = (f32x4){0.f, 0.f, 0.f, 0.f};

  #pragma unroll
  for (int ks = 0; ks < 4; ++ks) {
    const int jb = 32 * ks + 8 * g;
    const f32x4 pa0 = *(const f32x4*)&sm[pAo + jb];
    const f32x4 pa1 = *(const f32x4*)&sm[pAo + jb + 4];
    const f32x4 pb0 = *(const f32x4*)&sm[pBo + jb];
    const f32x4 pb1 = *(const f32x4*)&sm[pBo + jb + 4];
    const f32x4 b10 = *(const f32x4*)&sm[L_TAIL + net * 128 + jb];
    const f32x4 b11 = *(const f32x4*)&sm[L_TAIL + net * 128 + jb + 4];
    float paf[8], pbf[8], b1f[8];
    #pragma unroll
    for (int i = 0; i < 4; ++i) {
      paf[i] = pa0[i]; paf[4 + i] = pa1[i];
      pbf[i] = pb0[i]; pbf[4 + i] = pb1[i];
      b1f[i] = b10[i]; b1f[4 + i] = b11[i];
    }
    bf16x8 hb[2];
    #pragma unroll
    for (int c = 0; c < 2; ++c) {
      bf16x8 a;
      #pragma unroll
      for (int i = 0; i < 8; ++i)
        a[i] = (__bf16)fmaxf(fmaf(sAr[c], paf[i], fmaf(sBr[c], pbf[i], b1f[i])), 0.f);
      hb[c] = a;
    }
    #pragma unroll
    for (int mt = 0; mt < 4; ++mt) {
      const bf16x8 a = *(const bf16x8*)(wfb + (mt * 4 + ks) * 1024 + lane * 16);
      acc2[0][mt] = __builtin_amdgcn_mfma_f32_16x16x32_bf16(a, hb[0], acc2[0][mt], 0, 0, 0);
      acc2[1][mt] = __builtin_amdgcn_mfma_f32_16x16x32_bf16(a, hb[1], acc2[1][mt], 0, 0, 0);
    }
  }

  // ---- per-chunk: h2 epilogue -> L3 -> h3 epilogue -> L4+L5
  #pragma unroll
  for (int c = 0; c < 2; ++c) {
    #pragma unroll
    for (int mt = 0; mt < 4; ++mt) {
      const f32x4 b2v = *(const f32x4*)&sm[L_TAIL + 256 + net * 64 + 16 * mt + 4 * g];
      const f32x4 x = acc2[c][mt];
      union { __bf16 e[4]; u32x2 w; } o;
      #pragma unroll
      for (int r = 0; r < 4; ++r) o.e[r] = (__bf16)fmaxf(x[r] + b2v[r], 0.f);
      const int S = (2 * mt + (g >> 1)) ^ t7;
      *(u32x2*)(h2t + c16 * 128 + S * 16 + (g & 1) * 8) = o.w;
    }

    // layer 3: h3^T = W3^T @ h2^T
    f32x4 acc3[2];
    #pragma unroll
    for (int mt = 0; mt < 2; ++mt) acc3[mt] = (f32x4){0.f, 0.f, 0.f, 0.f};
    #pragma unroll
    for (int ks = 0; ks < 2; ++ks) {
      const int S = (4 * ks + g) ^ t7;
      const bf16x8 hbf = *(const bf16x8*)(h2t + c16 * 128 + S * 16);
      #pragma unroll
      for (int mt = 0; mt < 2; ++mt) {
        const bf16x8 a = *(const bf16x8*)(wfb + (16 + mt * 2 + ks) * 1024 + lane * 16);
        acc3[mt] = __builtin_amdgcn_mfma_f32_16x16x32_bf16(a, hbf, acc3[mt], 0, 0, 0);
      }
    }
    #pragma unroll
    for (int mt = 0; mt < 2; ++mt) {
      const f32x4 b3v = *(const f32x4*)&sm[L_TAIL + 384 + net * 32 + 16 * mt + 4 * g];
      const f32x4 x = acc3[mt];
      union { __bf16 e[4]; u32x2 w; } o;
      #pragma unroll
      for (int r = 0; r < 4; ++r) o.e[r] = (__bf16)fmaxf(x[r] + b3v[r], 0.f);
      const int S = (2 * mt + (g >> 1)) ^ t3;
      *(u32x2*)(h3t + c16 * 64 + S * 16 + (g & 1) * 8) = o.w;
    }

    // layer 4 + 5 + per-row reduce
    {
      const int S = g ^ t3;
      const bf16x8 hbf = *(const bf16x8*)(h3t + c16 * 64 + S * 16);
      const bf16x8 a = *(const bf16x8*)(wfb + 20 * 1024 + lane * 16);
      const f32x4 z = {0.f, 0.f, 0.f, 0.f};
      const f32x4 acc4 = __builtin_amdgcn_mfma_f32_16x16x32_bf16(a, hbf, z, 0, 0, 0);
      const f32x4 b4v = *(const f32x4*)&sm[L_TAIL + 448 + net * 16 + 4 * g];
      const f32x4 w5v = *(const f32x4*)&sm[L_TAIL + 480 + net * 16 + 4 * g];
      float v = 0.f;
      #pragma unroll
      for (int r = 0; r < 4; ++r)
        v = fmaf(fmaxf(acc4[r] + b4v[r], 0.f), w5v[r], v);   // pad cols: b4=w5=0
      v += __shfl_xor(v, 16); v += __shfl_xor(v, 32);
      const int lr = 16 * c + c16;
      if (g == 0 && lr < 25)
        sm[L_C + net * 128 + r0 + lr] = v + b5v;
    }
  }
  __syncthreads();

  // ---- final: sum rows 0..99 of both nets -> sigmoid(mean)
  float v = 0.f;
  if (tid < KDIM) v = sm[L_C + tid] + sm[L_C + 128 + tid];
  if (tid < 128) {
    #pragma unroll
    for (int d = 1; d < 64; d <<= 1) v += __shfl_xor(v, d);
    if ((tid & 63) == 0) sm[tid >> 6] = v;
  }
  __syncthreads();
  if (tid == 0) out[b] = 1.f / (1.f + expf(-0.01f * (sm[0] + sm[1])));
}

extern "C" void kernel_launch(void* const* d_in, const int* in_sizes, int n_in,
                              void* d_out, int out_size, void* d_ws, size_t ws_size,
                              hipStream_t stream) {
  const int*   user_idxs = (const int*)d_in[0];
  const int*   item_idxs = (const int*)d_in[1];
  const int*   uidx_t    = (const int*)d_in[2];
  const int*   iidx_t    = (const int*)d_in[3];
  const float* uscr      = (const float*)d_in[4];
  const float* iscr      = (const float*)d_in[5];
  const float* uemb      = (const float*)d_in[6];
  const float* iemb      = (const float*)d_in[7];

  const int B  = in_sizes[0];
  const int NU = in_sizes[6] / DDIM;
  const int NI = in_sizes[7] / DDIM;

  Weights N1 { (const float*)d_in[8],  (const float*)d_in[9],
               (const float*)d_in[10], (const float*)d_in[11],
               (const float*)d_in[12], (const float*)d_in[13],
               (const float*)d_in[14], (const float*)d_in[15],
               (const float*)d_in[16], (const float*)d_in[17] };
  Weights N2 { (const float*)d_in[18], (const float*)d_in[19],
               (const float*)d_in[20], (const float*)d_in[21],
               (const float*)d_in[22], (const float*)d_in[23],
               (const float*)d_in[24], (const float*)d_in[25],
               (const float*)d_in[26], (const float*)d_in[27] };

  char* ws = (char*)d_ws;
  float* u_rowsum = (float*)ws;
  float* i_rowsum = u_rowsum + NU;
  size_t off = (((size_t)(NU + NI) * 4 + 1023) & ~(size_t)1023);
  __bf16* wfrag = (__bf16*)(ws + off);                 // 42*512 bf16 = 43008 B
  float*  tail  = (float*)(wfrag + (size_t)42 * 512);  // 512 f32
  off += (((size_t)42 * 512 * 2 + 512 * 4 + 1023) & ~(size_t)1023);
  float* VG  = (float*)(ws + off);                     // [4][B][100]
  off += (size_t)4 * B * KDIM * 4;
  float* PAG = (float*)(ws + off);                     // [4][B][128]

  float* out = (float*)d_out;

  prep_kernel<<<1024, 256, 0, stream>>>(uemb, iemb, u_rowsum, i_rowsum, NU, NI, N1, N2, wfrag, tail);
  const int nbt = (B + 15) / 16;
  proj_kernel<<<nbt * 4, 256, 0, stream>>>(user_idxs, item_idxs, uidx_t, iidx_t,
                                           uscr, iscr, u_rowsum, i_rowsum,
                                           N1.w1, N2.w1, VG, PAG, B);
  mlp_kernel<<<B, 512, 0, stream>>>(VG, PAG, tail, N1.b5, N2.b5, wfrag, out, B);
}